// Round 1
// baseline (241.730 us; speedup 1.0000x reference)
//
#include <hip/hip_runtime.h>

#define LSEQ 384
#define NROWS 1536      // B*L
#define FDIM 640
#define HDIM 128

// ws layout (float indices)
#define WS_H1   0
#define WS_FI   196608
#define WS_FJ   393216
#define WS_QC   589824
#define WS_FLAG 591360   // int[1536]
#define WS_CNT  592896   // uint[1]
#define WS_LIST 592900   // uint[CAP]
#define CAPMAX  65536

// out layout (float indices)
#define OUT_PC    0
#define OUT_TC    4608
#define OUT_NET   9216
#define OUT_POT   10752
#define OUT_MASK  12288
#define OUT_EN    602112

// ---------------- Kernel 1: Y = X @ [W1 | a | b]  (M=1536, K=640, N=3x128) ----------------
// grid (96, 6): y -> mat = y>>1, half = y&1. BM=16, BN=64, BK=32, 128 threads.
__global__ __launch_bounds__(128) void k_gemm(const float* __restrict__ X,
                                              const float* __restrict__ W1,
                                              const float* __restrict__ sW1,
                                              float* __restrict__ ws) {
    __shared__ float As[32][17];   // [k][m], padded
    __shared__ float Bs[32][64];   // [k][n]
    const int t  = threadIdx.x;
    const int m0 = blockIdx.x * 16;
    const int gy = blockIdx.y;
    const int mat = gy >> 1, half = gy & 1, n0 = half * 64;
    const float* W = (mat == 0) ? W1 : (mat == 1 ? sW1 : sW1 + 640 * 128);
    float* O = ws + (mat == 0 ? WS_H1 : (mat == 1 ? WS_FI : WS_FJ));

    const int a_row = t >> 3;            // 0..15
    const int a_c4  = (t & 7) * 4;       // 0..28
    const int b_c4  = (t & 15) * 4;      // 0..60
    const int b_r   = t >> 4;            // 0..7
    const int tx    = (t & 15) * 4;      // n local
    const int ty    = (t >> 4) * 2;      // m local

    float acc[2][4] = {};

    for (int kk = 0; kk < FDIM; kk += 32) {
        float4 av = *(const float4*)&X[(m0 + a_row) * FDIM + kk + a_c4];
        As[a_c4 + 0][a_row] = av.x;
        As[a_c4 + 1][a_row] = av.y;
        As[a_c4 + 2][a_row] = av.z;
        As[a_c4 + 3][a_row] = av.w;
#pragma unroll
        for (int q = 0; q < 4; q++) {
            int r = b_r + q * 8;
            *(float4*)&Bs[r][b_c4] = *(const float4*)&W[(kk + r) * HDIM + n0 + b_c4];
        }
        __syncthreads();
#pragma unroll
        for (int k = 0; k < 32; k++) {
            float a0 = As[k][ty], a1 = As[k][ty + 1];
            float4 bv = *(const float4*)&Bs[k][tx];
            acc[0][0] = fmaf(a0, bv.x, acc[0][0]);
            acc[0][1] = fmaf(a0, bv.y, acc[0][1]);
            acc[0][2] = fmaf(a0, bv.z, acc[0][2]);
            acc[0][3] = fmaf(a0, bv.w, acc[0][3]);
            acc[1][0] = fmaf(a1, bv.x, acc[1][0]);
            acc[1][1] = fmaf(a1, bv.y, acc[1][1]);
            acc[1][2] = fmaf(a1, bv.z, acc[1][2]);
            acc[1][3] = fmaf(a1, bv.w, acc[1][3]);
        }
        __syncthreads();
    }
#pragma unroll
    for (int r = 0; r < 2; r++) {
        float4 v = make_float4(acc[r][0], acc[r][1], acc[r][2], acc[r][3]);
        *(float4*)&O[(m0 + ty + r) * HDIM + n0 + tx] = v;
    }
}

// ---------------- Kernel 2: per-row epilogue ----------------
// grid 1536, block 128
__global__ __launch_bounds__(128) void k_row(const float* __restrict__ h1pre,
                                             const float* __restrict__ b1,
                                             const float* __restrict__ gam,
                                             const float* __restrict__ bet,
                                             const float* __restrict__ rmean,
                                             const float* __restrict__ rvar,
                                             const float* __restrict__ W2,
                                             const float* __restrict__ b2,
                                             const float* __restrict__ W3,
                                             const float* __restrict__ b3,
                                             const int* __restrict__ seq,
                                             float* __restrict__ out,
                                             float* __restrict__ qc,
                                             int* __restrict__ flags) {
    __shared__ float sh[128];
    __shared__ float sh2[64];
    __shared__ float lg[3];
    const int row = blockIdx.x, t = threadIdx.x;
    {
        float v = h1pre[row * HDIM + t] + b1[t];
        v = fmaxf(v, 0.0f);
        v = gam[t] * (v - rmean[t]) / sqrtf(rvar[t] + 1e-5f) + bet[t];
        sh[t] = v;
    }
    __syncthreads();
    if (t < 64) {
        float acc = b2[t];
        for (int c = 0; c < 128; c++) acc = fmaf(sh[c], W2[c * 64 + t], acc);
        sh2[t] = fmaxf(acc, 0.0f);
    }
    __syncthreads();
    if (t < 3) {
        float acc = b3[t];
        for (int c = 0; c < 64; c++) acc = fmaf(sh2[c], W3[c * 3 + t], acc);
        lg[t] = acc;
    }
    __syncthreads();
    if (t == 0) {
        float l0 = lg[0], l1 = lg[1], l2 = lg[2];
        float m = fmaxf(l0, fmaxf(l1, l2));
        float e0 = expf(l0 - m), e1 = expf(l1 - m), e2 = expf(l2 - m);
        float s = e0 + e1 + e2;
        float pc0 = e0 / s, pc1 = e1 / s, pc2 = e2 / s;
        out[OUT_PC + row * 3 + 0] = pc0;
        out[OUT_PC + row * 3 + 1] = pc1;
        out[OUT_PC + row * 3 + 2] = pc2;
        float net = pc0 - pc1;
        out[OUT_NET + row] = net;
        qc[row] = net;
        flags[row] = (pc0 > pc2 ? 1 : 0) | (pc1 > pc2 ? 2 : 0);
        int sid = seq[row];
        float c0 = (sid == 6 || sid == 8 || sid == 14) ? 1.0f : 0.0f;
        float c1 = (sid == 2 || sid == 3) ? 1.0f : 0.0f;
        out[OUT_TC + row * 3 + 0] = c0;
        out[OUT_TC + row * 3 + 1] = c1;
        out[OUT_TC + row * 3 + 2] = (c0 == 0.0f && c1 == 0.0f) ? 1.0f : 0.0f;
    }
}

// ---------------- Kernel 3: conv stack + zero energy/counter ----------------
// grid 4, block 384
__global__ __launch_bounds__(384) void k_conv(const float* __restrict__ net,
                                              const float* __restrict__ c1w, const float* __restrict__ c1b,
                                              const float* __restrict__ c2w, const float* __restrict__ c2b,
                                              const float* __restrict__ c3w, const float* __restrict__ c3b,
                                              float* __restrict__ out,
                                              unsigned int* __restrict__ cnt) {
    __shared__ float p0[LSEQ + 4];
    __shared__ float p1[16][LSEQ + 2];
    __shared__ float p2[8][LSEQ + 2];
    const int b = blockIdx.x, t = threadIdx.x;
    p0[t + 2] = net[b * LSEQ + t];
    if (t < 2) { p0[t] = 0.0f; p0[LSEQ + 2 + t] = 0.0f; }
    if (t < 16) { p1[t][0] = 0.0f; p1[t][LSEQ + 1] = 0.0f; }
    if (t < 8)  { p2[t][0] = 0.0f; p2[t][LSEQ + 1] = 0.0f; }
    if (b == 0) {
        if (t < 4) out[OUT_EN + t] = 0.0f;
        if (t == 4) *cnt = 0u;
    }
    __syncthreads();
#pragma unroll
    for (int o = 0; o < 16; o++) {
        float acc = c1b[o];
#pragma unroll
        for (int k = 0; k < 5; k++) acc = fmaf(p0[t + k], c1w[o * 5 + k], acc);
        p1[o][t + 1] = fmaxf(acc, 0.0f);
    }
    __syncthreads();
#pragma unroll
    for (int o = 0; o < 8; o++) {
        float acc = c2b[o];
        for (int i = 0; i < 16; i++)
#pragma unroll
            for (int k = 0; k < 3; k++)
                acc = fmaf(p1[i][t + k], c2w[(o * 16 + i) * 3 + k], acc);
        p2[o][t + 1] = fmaxf(acc, 0.0f);
    }
    __syncthreads();
    {
        float acc = c3b[0];
        for (int i = 0; i < 8; i++)
#pragma unroll
            for (int k = 0; k < 3; k++)
                acc = fmaf(p2[i][t + k], c3w[i * 3 + k], acc);
        out[OUT_POT + b * LSEQ + t] = acc;
    }
}

// ---------------- Kernel 4: pair sweep (mask zeros, energy, candidate list) ----------------
// grid 1536 (= b*L+i), block 256
__global__ __launch_bounds__(256) void k_pair(const float* __restrict__ S,
                                              const float* __restrict__ qc,
                                              const int* __restrict__ flags,
                                              float* __restrict__ out,
                                              unsigned int* __restrict__ cnt,
                                              unsigned int* __restrict__ list,
                                              unsigned int cap) {
    __shared__ float sx[LSEQ], sy[LSEQ], sz[LSEQ], sq[LSEQ];
    __shared__ int sf[LSEQ];
    __shared__ float red[4];
    const int row = blockIdx.x;
    const int b = row / LSEQ;
    const int i = row - b * LSEQ;
    const int t = threadIdx.x;
    for (int j = t; j < LSEQ; j += 256) {
        int g = b * LSEQ + j;
        sx[j] = S[g * 3 + 0];
        sy[j] = S[g * 3 + 1];
        sz[j] = S[g * 3 + 2];
        sq[j] = qc[g];
        sf[j] = flags[g];
    }
    __syncthreads();
    const float six = sx[i], siy = sy[i], siz = sz[i], qi = sq[i];
    const bool posi = (sf[i] & 1) != 0;
    const int lane = t & 63;
    float esum = 0.0f;
    float* mrow = out + OUT_MASK + (long)row * LSEQ;
    for (int j = t; j < LSEQ; j += 256) {
        float dx = __fsub_rn(six, sx[j]);
        float dy = __fsub_rn(siy, sy[j]);
        float dz = __fsub_rn(siz, sz[j]);
        float d2 = __fadd_rn(__fadd_rn(__fmul_rn(dx, dx), __fmul_rn(dy, dy)), __fmul_rn(dz, dz));
        d2 = __fadd_rn(d2, 1e-12f);
        float D = __fsqrt_rn(d2);
        mrow[j] = 0.0f;
        if (j > i && D < 15.0f && D > 0.0f) {
            float num = __fmul_rn(__fmul_rn(332.0f, qi), sq[j]);
            float den = __fmul_rn(__fmul_rn(20.0f, D), D);
            esum += __fdiv_rn(num, den);
        }
        bool cand = posi && ((sf[j] & 2) != 0) && (D < 4.0f);
        unsigned long long mball = __ballot(cand);
        int nc = __popcll(mball);
        unsigned int base = 0;
        if (lane == 0 && nc > 0) base = atomicAdd(cnt, (unsigned int)nc);
        base = __shfl(base, 0, 64);
        if (cand) {
            int off = __popcll(mball & ((1ull << lane) - 1ull));
            unsigned int p = base + (unsigned int)off;
            if (p < cap) list[p] = ((unsigned int)row << 9) | (unsigned int)j;
        }
    }
    for (int o = 32; o > 0; o >>= 1) esum += __shfl_xor(esum, o, 64);
    if (lane == 0) red[t >> 6] = esum;
    __syncthreads();
    if (t == 0) {
        float s = red[0] + red[1] + red[2] + red[3];
        atomicAdd(&out[OUT_EN + b], s);
    }
}

// ---------------- Kernel 5: candidate MLP -> mask scatter ----------------
// grid 64, block 256 (one wave per candidate, strided)
__global__ __launch_bounds__(256) void k_cand(const float* __restrict__ S,
                                              const float* __restrict__ fi,
                                              const float* __restrict__ fj,
                                              const float* __restrict__ sW1,
                                              const float* __restrict__ sb1,
                                              const float* __restrict__ sW2,
                                              const float* __restrict__ sb2,
                                              const float* __restrict__ sW3,
                                              const float* __restrict__ sb3,
                                              const unsigned int* __restrict__ cnt,
                                              const unsigned int* __restrict__ list,
                                              float* __restrict__ out,
                                              unsigned int cap) {
    const float* dvec = sW1 + 1280 * 128;
    const int gid = blockIdx.x * 256 + threadIdx.x;
    const int gw = gid >> 6;
    const int lane = gid & 63;
    const int nw = (gridDim.x * 256) >> 6;
    unsigned int n = *cnt;
    if (n > cap) n = cap;
    const float w3 = sW3[lane];
    const float bias2 = sb2[lane];
    const float b3v = sb3[0];
    float* mask = out + OUT_MASK;
    for (unsigned int c = (unsigned int)gw; c < n; c += (unsigned int)nw) {
        unsigned int v = list[c];
        int row = (int)(v >> 9);
        int j = (int)(v & 511u);
        int i = row % LSEQ;
        int rowB = row - i;
        int col = rowB + j;
        float dx = __fsub_rn(S[row * 3 + 0], S[col * 3 + 0]);
        float dy = __fsub_rn(S[row * 3 + 1], S[col * 3 + 1]);
        float dz = __fsub_rn(S[row * 3 + 2], S[col * 3 + 2]);
        float d2 = __fadd_rn(__fadd_rn(__fmul_rn(dx, dx), __fmul_rn(dy, dy)), __fmul_rn(dz, dz));
        d2 = __fadd_rn(d2, 1e-12f);
        float D = __fsqrt_rn(d2);
        float acc = bias2;
        const float* fip = fi + (long)row * 128;
        const float* fjp = fj + (long)col * 128;
        for (int cc = 0; cc < 128; cc++) {
            float h = fip[cc] + fjp[cc] + D * dvec[cc] + sb1[cc];
            h = fmaxf(h, 0.0f);
            acc = fmaf(h, sW2[cc * 64 + lane], acc);
        }
        float x = fmaxf(acc, 0.0f) * w3;
        for (int o = 32; o > 0; o >>= 1) x += __shfl_xor(x, o, 64);
        if (lane == 0 && (x + b3v) > 0.0f) {
            mask[(long)row * LSEQ + j] = 1.0f;
            mask[(long)col * LSEQ + i] = 1.0f;
        }
    }
}

extern "C" void kernel_launch(void* const* d_in, const int* in_sizes, int n_in,
                              void* d_out, int out_size, void* d_ws, size_t ws_size,
                              hipStream_t stream) {
    const float* X     = (const float*)d_in[0];
    const int*   seq   = (const int*)d_in[1];
    const float* S     = (const float*)d_in[2];
    const float* W1    = (const float*)d_in[3];
    const float* b1    = (const float*)d_in[4];
    const float* gam   = (const float*)d_in[5];
    const float* bet   = (const float*)d_in[6];
    const float* rmean = (const float*)d_in[7];
    const float* rvar  = (const float*)d_in[8];
    const float* W2    = (const float*)d_in[9];
    const float* b2    = (const float*)d_in[10];
    const float* W3    = (const float*)d_in[11];
    const float* b3    = (const float*)d_in[12];
    const float* sW1   = (const float*)d_in[13];
    const float* sb1   = (const float*)d_in[14];
    const float* sW2   = (const float*)d_in[15];
    const float* sb2   = (const float*)d_in[16];
    const float* sW3   = (const float*)d_in[17];
    const float* sb3   = (const float*)d_in[18];
    const float* c1w   = (const float*)d_in[19];
    const float* c1b   = (const float*)d_in[20];
    const float* c2w   = (const float*)d_in[21];
    const float* c2b   = (const float*)d_in[22];
    const float* c3w   = (const float*)d_in[23];
    const float* c3b   = (const float*)d_in[24];

    float* out = (float*)d_out;
    float* ws  = (float*)d_ws;
    unsigned int* cnt  = (unsigned int*)(ws + WS_CNT);
    unsigned int* list = (unsigned int*)(ws + WS_LIST);
    int* flags = (int*)(ws + WS_FLAG);

    unsigned int cap = 0;
    size_t ws_floats = ws_size / 4;
    if (ws_floats > (size_t)WS_LIST) {
        size_t room = ws_floats - WS_LIST;
        cap = (unsigned int)(room < CAPMAX ? room : CAPMAX);
    }

    hipLaunchKernelGGL(k_gemm, dim3(96, 6), dim3(128), 0, stream, X, W1, sW1, ws);
    hipLaunchKernelGGL(k_row, dim3(1536), dim3(128), 0, stream,
                       ws + WS_H1, b1, gam, bet, rmean, rvar, W2, b2, W3, b3,
                       seq, out, ws + WS_QC, flags);
    hipLaunchKernelGGL(k_conv, dim3(4), dim3(384), 0, stream,
                       out + OUT_NET, c1w, c1b, c2w, c2b, c3w, c3b, out, cnt);
    hipLaunchKernelGGL(k_pair, dim3(1536), dim3(256), 0, stream,
                       S, ws + WS_QC, flags, out, cnt, list, cap);
    hipLaunchKernelGGL(k_cand, dim3(64), dim3(256), 0, stream,
                       S, ws + WS_FI, ws + WS_FJ, sW1, sb1, sW2, sb2, sW3, sb3,
                       cnt, list, out, cap);
}

// Round 2
// 194.628 us; speedup vs baseline: 1.2420x; 1.2420x over previous
//
#include <hip/hip_runtime.h>

#define LSEQ 384
#define NROWS 1536      // B*L
#define FDIM 640
#define HDIM 128

// ws layout (float indices)
#define WS_H1   0
#define WS_FI   196608
#define WS_FJ   393216
#define WS_QC   589824
#define WS_FLAG 591360   // int[1536]
#define WS_CNT  592896   // uint[1]
#define WS_LIST 592900   // uint[CAP]
#define CAPMAX  65536

// out layout (float indices)
#define OUT_PC    0
#define OUT_TC    4608
#define OUT_NET   9216
#define OUT_POT   10752
#define OUT_MASK  12288
#define OUT_EN    602112

// ---------------- Kernel 1: Y = X @ [W1 | a | b]  (M=1536, K=640, N=3x128) ----------------
// grid (48, 6): y -> mat = y>>1, half = y&1. BM=32, BN=64, BK=32, 128 threads, acc 4x4.
__global__ __launch_bounds__(128) void k_gemm(const float* __restrict__ X,
                                              const float* __restrict__ W1,
                                              const float* __restrict__ sW1,
                                              float* __restrict__ ws) {
    __shared__ float As[32][36];   // [k][m], pad to 36 (144B rows, 16B-aligned)
    __shared__ float Bs[32][64];   // [k][n]
    const int t  = threadIdx.x;
    const int m0 = blockIdx.x * 32;
    const int gy = blockIdx.y;
    const int mat = gy >> 1, half = gy & 1, n0 = half * 64;
    const float* W = (mat == 0) ? W1 : (mat == 1 ? sW1 : sW1 + 640 * 128);
    float* O = ws + (mat == 0 ? WS_H1 : (mat == 1 ? WS_FI : WS_FJ));

    const int a_r  = t >> 2;             // 0..31
    const int a_c8 = (t & 3) * 8;        // 0,8,16,24
    const int b_r  = t >> 4;             // 0..7
    const int b_c4 = (t & 15) * 4;       // 0..60
    const int tx   = (t & 15) * 4;       // n local
    const int ty   = (t >> 4) * 4;       // m local

    float acc[4][4] = {};

    for (int kk = 0; kk < FDIM; kk += 32) {
        float4 av0 = *(const float4*)&X[(m0 + a_r) * FDIM + kk + a_c8];
        float4 av1 = *(const float4*)&X[(m0 + a_r) * FDIM + kk + a_c8 + 4];
        As[a_c8 + 0][a_r] = av0.x;
        As[a_c8 + 1][a_r] = av0.y;
        As[a_c8 + 2][a_r] = av0.z;
        As[a_c8 + 3][a_r] = av0.w;
        As[a_c8 + 4][a_r] = av1.x;
        As[a_c8 + 5][a_r] = av1.y;
        As[a_c8 + 6][a_r] = av1.z;
        As[a_c8 + 7][a_r] = av1.w;
#pragma unroll
        for (int q = 0; q < 4; q++) {
            int r = b_r + q * 8;
            *(float4*)&Bs[r][b_c4] = *(const float4*)&W[(kk + r) * HDIM + n0 + b_c4];
        }
        __syncthreads();
#pragma unroll 8
        for (int k = 0; k < 32; k++) {
            float4 a = *(const float4*)&As[k][ty];
            float4 b = *(const float4*)&Bs[k][tx];
            float ar[4] = {a.x, a.y, a.z, a.w};
            float br[4] = {b.x, b.y, b.z, b.w};
#pragma unroll
            for (int i = 0; i < 4; i++)
#pragma unroll
                for (int j = 0; j < 4; j++)
                    acc[i][j] = fmaf(ar[i], br[j], acc[i][j]);
        }
        __syncthreads();
    }
#pragma unroll
    for (int r = 0; r < 4; r++) {
        float4 v = make_float4(acc[r][0], acc[r][1], acc[r][2], acc[r][3]);
        *(float4*)&O[(m0 + ty + r) * HDIM + n0 + tx] = v;
    }
}

// ---------------- Kernel 2: per-row epilogue ----------------
// grid 1536, block 128
__global__ __launch_bounds__(128) void k_row(const float* __restrict__ h1pre,
                                             const float* __restrict__ b1,
                                             const float* __restrict__ gam,
                                             const float* __restrict__ bet,
                                             const float* __restrict__ rmean,
                                             const float* __restrict__ rvar,
                                             const float* __restrict__ W2,
                                             const float* __restrict__ b2,
                                             const float* __restrict__ W3,
                                             const float* __restrict__ b3,
                                             const int* __restrict__ seq,
                                             float* __restrict__ out,
                                             float* __restrict__ qc,
                                             int* __restrict__ flags) {
    __shared__ float sh[128];
    __shared__ float sh2[64];
    __shared__ float lg[3];
    const int row = blockIdx.x, t = threadIdx.x;
    {
        float v = h1pre[row * HDIM + t] + b1[t];
        v = fmaxf(v, 0.0f);
        v = gam[t] * (v - rmean[t]) / sqrtf(rvar[t] + 1e-5f) + bet[t];
        sh[t] = v;
    }
    __syncthreads();
    if (t < 64) {
        float acc = b2[t];
        for (int c = 0; c < 128; c++) acc = fmaf(sh[c], W2[c * 64 + t], acc);
        sh2[t] = fmaxf(acc, 0.0f);
    }
    __syncthreads();
    if (t < 3) {
        float acc = b3[t];
        for (int c = 0; c < 64; c++) acc = fmaf(sh2[c], W3[c * 3 + t], acc);
        lg[t] = acc;
    }
    __syncthreads();
    if (t == 0) {
        float l0 = lg[0], l1 = lg[1], l2 = lg[2];
        float m = fmaxf(l0, fmaxf(l1, l2));
        float e0 = expf(l0 - m), e1 = expf(l1 - m), e2 = expf(l2 - m);
        float s = e0 + e1 + e2;
        float pc0 = e0 / s, pc1 = e1 / s, pc2 = e2 / s;
        out[OUT_PC + row * 3 + 0] = pc0;
        out[OUT_PC + row * 3 + 1] = pc1;
        out[OUT_PC + row * 3 + 2] = pc2;
        float net = pc0 - pc1;
        out[OUT_NET + row] = net;
        qc[row] = net;
        flags[row] = (pc0 > pc2 ? 1 : 0) | (pc1 > pc2 ? 2 : 0);
        int sid = seq[row];
        float c0 = (sid == 6 || sid == 8 || sid == 14) ? 1.0f : 0.0f;
        float c1 = (sid == 2 || sid == 3) ? 1.0f : 0.0f;
        out[OUT_TC + row * 3 + 0] = c0;
        out[OUT_TC + row * 3 + 1] = c1;
        out[OUT_TC + row * 3 + 2] = (c0 == 0.0f && c1 == 0.0f) ? 1.0f : 0.0f;
    }
}

// ---------------- Kernel 3: conv stack + zero energy/counter ----------------
// grid 4, block 384
__global__ __launch_bounds__(384) void k_conv(const float* __restrict__ net,
                                              const float* __restrict__ c1w, const float* __restrict__ c1b,
                                              const float* __restrict__ c2w, const float* __restrict__ c2b,
                                              const float* __restrict__ c3w, const float* __restrict__ c3b,
                                              float* __restrict__ out,
                                              unsigned int* __restrict__ cnt) {
    __shared__ float p0[LSEQ + 4];
    __shared__ float p1[16][LSEQ + 2];
    __shared__ float p2[8][LSEQ + 2];
    const int b = blockIdx.x, t = threadIdx.x;
    p0[t + 2] = net[b * LSEQ + t];
    if (t < 2) { p0[t] = 0.0f; p0[LSEQ + 2 + t] = 0.0f; }
    if (t < 16) { p1[t][0] = 0.0f; p1[t][LSEQ + 1] = 0.0f; }
    if (t < 8)  { p2[t][0] = 0.0f; p2[t][LSEQ + 1] = 0.0f; }
    if (b == 0) {
        if (t < 4) out[OUT_EN + t] = 0.0f;
        if (t == 4) *cnt = 0u;
    }
    __syncthreads();
#pragma unroll
    for (int o = 0; o < 16; o++) {
        float acc = c1b[o];
#pragma unroll
        for (int k = 0; k < 5; k++) acc = fmaf(p0[t + k], c1w[o * 5 + k], acc);
        p1[o][t + 1] = fmaxf(acc, 0.0f);
    }
    __syncthreads();
#pragma unroll
    for (int o = 0; o < 8; o++) {
        float acc = c2b[o];
        for (int i = 0; i < 16; i++)
#pragma unroll
            for (int k = 0; k < 3; k++)
                acc = fmaf(p1[i][t + k], c2w[(o * 16 + i) * 3 + k], acc);
        p2[o][t + 1] = fmaxf(acc, 0.0f);
    }
    __syncthreads();
    {
        float acc = c3b[0];
        for (int i = 0; i < 8; i++)
#pragma unroll
            for (int k = 0; k < 3; k++)
                acc = fmaf(p2[i][t + k], c3w[i * 3 + k], acc);
        out[OUT_POT + b * LSEQ + t] = acc;
    }
}

// ---------------- Kernel 4: pair sweep (mask zeros, energy, candidate list) ----------------
// grid 1536 (= b*L+i), block 256
__global__ __launch_bounds__(256) void k_pair(const float* __restrict__ S,
                                              const float* __restrict__ qc,
                                              const int* __restrict__ flags,
                                              float* __restrict__ out,
                                              unsigned int* __restrict__ cnt,
                                              unsigned int* __restrict__ list,
                                              unsigned int cap) {
    __shared__ float sx[LSEQ], sy[LSEQ], sz[LSEQ], sq[LSEQ];
    __shared__ int sf[LSEQ];
    __shared__ float red[4];
    const int row = blockIdx.x;
    const int b = row / LSEQ;
    const int i = row - b * LSEQ;
    const int t = threadIdx.x;
    for (int j = t; j < LSEQ; j += 256) {
        int g = b * LSEQ + j;
        sx[j] = S[g * 3 + 0];
        sy[j] = S[g * 3 + 1];
        sz[j] = S[g * 3 + 2];
        sq[j] = qc[g];
        sf[j] = flags[g];
    }
    __syncthreads();
    const float six = sx[i], siy = sy[i], siz = sz[i], qi = sq[i];
    const bool posi = (sf[i] & 1) != 0;
    const int lane = t & 63;
    float esum = 0.0f;
    float* mrow = out + OUT_MASK + (long)row * LSEQ;
    for (int j = t; j < LSEQ; j += 256) {
        float dx = __fsub_rn(six, sx[j]);
        float dy = __fsub_rn(siy, sy[j]);
        float dz = __fsub_rn(siz, sz[j]);
        float d2 = __fadd_rn(__fadd_rn(__fmul_rn(dx, dx), __fmul_rn(dy, dy)), __fmul_rn(dz, dz));
        d2 = __fadd_rn(d2, 1e-12f);
        float D = __fsqrt_rn(d2);
        mrow[j] = 0.0f;
        if (j > i && D < 15.0f && D > 0.0f) {
            float num = __fmul_rn(__fmul_rn(332.0f, qi), sq[j]);
            float den = __fmul_rn(__fmul_rn(20.0f, D), D);
            esum += __fdiv_rn(num, den);
        }
        bool cand = posi && ((sf[j] & 2) != 0) && (D < 4.0f);
        unsigned long long mball = __ballot(cand);
        int nc = __popcll(mball);
        unsigned int base = 0;
        if (lane == 0 && nc > 0) base = atomicAdd(cnt, (unsigned int)nc);
        base = __shfl(base, 0, 64);
        if (cand) {
            int off = __popcll(mball & ((1ull << lane) - 1ull));
            unsigned int p = base + (unsigned int)off;
            if (p < cap) list[p] = ((unsigned int)row << 9) | (unsigned int)j;
        }
    }
    for (int o = 32; o > 0; o >>= 1) esum += __shfl_xor(esum, o, 64);
    if (lane == 0) red[t >> 6] = esum;
    __syncthreads();
    if (t == 0) {
        float s = red[0] + red[1] + red[2] + red[3];
        atomicAdd(&out[OUT_EN + b], s);
    }
}

// ---------------- Kernel 5: candidate MLP -> mask scatter ----------------
// grid 192, block 256 (one wave per candidate, strided). sW2 staged in LDS;
// h kept in registers, broadcast via v_readlane (no global loads in the chain).
__global__ __launch_bounds__(256) void k_cand(const float* __restrict__ S,
                                              const float* __restrict__ fi,
                                              const float* __restrict__ fj,
                                              const float* __restrict__ sW1,
                                              const float* __restrict__ sb1,
                                              const float* __restrict__ sW2,
                                              const float* __restrict__ sb2,
                                              const float* __restrict__ sW3,
                                              const float* __restrict__ sb3,
                                              const unsigned int* __restrict__ cnt,
                                              const unsigned int* __restrict__ list,
                                              float* __restrict__ out,
                                              unsigned int cap) {
    unsigned int n = *cnt;
    if (n > cap) n = cap;
    if (blockIdx.x * 4 >= n) return;   // block-uniform early out (before barrier)

    __shared__ float w2s[128 * 64];    // 32 KB, [cc][l]: 2 lanes/bank = free
    const int t = threadIdx.x;
    for (int idx = t; idx < 2048; idx += 256)
        ((float4*)w2s)[idx] = ((const float4*)sW2)[idx];

    const int lane = t & 63;
    const int w = t >> 6;
    const float* dvec = sW1 + 1280 * 128;
    const float dv0 = dvec[lane],    dv1 = dvec[lane + 64];
    const float sb0 = sb1[lane],     sb1v = sb1[lane + 64];
    const float w3  = sW3[lane];
    const float b2v = sb2[lane];
    const float b3v = sb3[0];
    float* mask = out + OUT_MASK;
    __syncthreads();

    const int gw = blockIdx.x * 4 + w;
    const int nw = gridDim.x * 4;
    for (unsigned int c = (unsigned int)gw; c < n; c += (unsigned int)nw) {
        unsigned int v = list[c];
        int row = (int)(v >> 9);
        int j = (int)(v & 511u);
        int i = row % LSEQ;
        int col = row - i + j;
        float dx = __fsub_rn(S[row * 3 + 0], S[col * 3 + 0]);
        float dy = __fsub_rn(S[row * 3 + 1], S[col * 3 + 1]);
        float dz = __fsub_rn(S[row * 3 + 2], S[col * 3 + 2]);
        float d2 = __fadd_rn(__fadd_rn(__fmul_rn(dx, dx), __fmul_rn(dy, dy)), __fmul_rn(dz, dz));
        d2 = __fadd_rn(d2, 1e-12f);
        float D = __fsqrt_rn(d2);
        float fi0 = fi[(long)row * 128 + lane];
        float fi1 = fi[(long)row * 128 + 64 + lane];
        float fj0 = fj[(long)col * 128 + lane];
        float fj1 = fj[(long)col * 128 + 64 + lane];
        float h0 = fmaxf(fi0 + fj0 + D * dv0 + sb0, 0.0f);
        float h1 = fmaxf(fi1 + fj1 + D * dv1 + sb1v, 0.0f);
        float acc0 = 0.0f, acc1 = 0.0f;
#pragma unroll
        for (int cc = 0; cc < 64; cc++) {
            float hv0 = __uint_as_float(__builtin_amdgcn_readlane(__float_as_uint(h0), cc));
            float hv1 = __uint_as_float(__builtin_amdgcn_readlane(__float_as_uint(h1), cc));
            acc0 = fmaf(hv0, w2s[cc * 64 + lane], acc0);
            acc1 = fmaf(hv1, w2s[(cc + 64) * 64 + lane], acc1);
        }
        float x = fmaxf(acc0 + acc1 + b2v, 0.0f) * w3;
        for (int o = 32; o > 0; o >>= 1) x += __shfl_xor(x, o, 64);
        if (lane == 0 && (x + b3v) > 0.0f) {
            mask[(long)row * LSEQ + j] = 1.0f;
            mask[(long)col * LSEQ + i] = 1.0f;
        }
    }
}

extern "C" void kernel_launch(void* const* d_in, const int* in_sizes, int n_in,
                              void* d_out, int out_size, void* d_ws, size_t ws_size,
                              hipStream_t stream) {
    const float* X     = (const float*)d_in[0];
    const int*   seq   = (const int*)d_in[1];
    const float* S     = (const float*)d_in[2];
    const float* W1    = (const float*)d_in[3];
    const float* b1    = (const float*)d_in[4];
    const float* gam   = (const float*)d_in[5];
    const float* bet   = (const float*)d_in[6];
    const float* rmean = (const float*)d_in[7];
    const float* rvar  = (const float*)d_in[8];
    const float* W2    = (const float*)d_in[9];
    const float* b2    = (const float*)d_in[10];
    const float* W3    = (const float*)d_in[11];
    const float* b3    = (const float*)d_in[12];
    const float* sW1   = (const float*)d_in[13];
    const float* sb1   = (const float*)d_in[14];
    const float* sW2   = (const float*)d_in[15];
    const float* sb2   = (const float*)d_in[16];
    const float* sW3   = (const float*)d_in[17];
    const float* sb3   = (const float*)d_in[18];
    const float* c1w   = (const float*)d_in[19];
    const float* c1b   = (const float*)d_in[20];
    const float* c2w   = (const float*)d_in[21];
    const float* c2b   = (const float*)d_in[22];
    const float* c3w   = (const float*)d_in[23];
    const float* c3b   = (const float*)d_in[24];

    float* out = (float*)d_out;
    float* ws  = (float*)d_ws;
    unsigned int* cnt  = (unsigned int*)(ws + WS_CNT);
    unsigned int* list = (unsigned int*)(ws + WS_LIST);
    int* flags = (int*)(ws + WS_FLAG);

    unsigned int cap = 0;
    size_t ws_floats = ws_size / 4;
    if (ws_floats > (size_t)WS_LIST) {
        size_t room = ws_floats - WS_LIST;
        cap = (unsigned int)(room < CAPMAX ? room : CAPMAX);
    }

    hipLaunchKernelGGL(k_gemm, dim3(48, 6), dim3(128), 0, stream, X, W1, sW1, ws);
    hipLaunchKernelGGL(k_row, dim3(1536), dim3(128), 0, stream,
                       ws + WS_H1, b1, gam, bet, rmean, rvar, W2, b2, W3, b3,
                       seq, out, ws + WS_QC, flags);
    hipLaunchKernelGGL(k_conv, dim3(4), dim3(384), 0, stream,
                       out + OUT_NET, c1w, c1b, c2w, c2b, c3w, c3b, out, cnt);
    hipLaunchKernelGGL(k_pair, dim3(1536), dim3(256), 0, stream,
                       S, ws + WS_QC, flags, out, cnt, list, cap);
    hipLaunchKernelGGL(k_cand, dim3(192), dim3(256), 0, stream,
                       S, ws + WS_FI, ws + WS_FJ, sW1, sb1, sW2, sb2, sW3, sb3,
                       cnt, list, out, cap);
}

// Round 3
// 189.980 us; speedup vs baseline: 1.2724x; 1.0245x over previous
//
#include <hip/hip_runtime.h>

#define LSEQ 384
#define NROWS 1536      // B*L
#define FDIM 640
#define HDIM 128
#define PART 196608     // 1536*128

// ws layout (float indices) -- split-K=2 partials
#define WS_H1   0              // parts at 0, 196608
#define WS_FI   393216         // parts at 393216, 589824
#define WS_FJ   786432         // parts at 786432, 983040
#define WS_QC   1179648
#define WS_FLAG 1181184        // int[1536]
#define WS_CNT  1182720        // uint[1]
#define WS_LIST 1182724        // uint[CAP]
#define CAPMAX  65536

// out layout (float indices)
#define OUT_PC    0
#define OUT_TC    4608
#define OUT_NET   9216
#define OUT_POT   10752
#define OUT_MASK  12288
#define OUT_EN    602112

// ---------------- Kernel 1: Y = X @ [W1 | a | b], split-K=2 ----------------
// grid (48, 6, 2): y -> mat = y>>1, half = y&1; z = K-split. BM=32 BN=64 BK=32, 256 thr.
__global__ __launch_bounds__(256) void k_gemm(const float* __restrict__ X,
                                              const float* __restrict__ W1,
                                              const float* __restrict__ sW1,
                                              float* __restrict__ ws) {
    __shared__ float As[32][34];   // [k][m], pad 34 keeps float2 8B-aligned
    __shared__ float Bs[32][64];   // [k][n]
    const int t  = threadIdx.x;
    const int m0 = blockIdx.x * 32;
    const int gy = blockIdx.y;
    const int kz = blockIdx.z;
    const int mat = gy >> 1, half = gy & 1, n0 = half * 64;
    const float* W = (mat == 0) ? W1 : (mat == 1 ? sW1 : sW1 + 640 * 128);
    float* O = ws + (mat == 0 ? WS_H1 : (mat == 1 ? WS_FI : WS_FJ)) + kz * PART;

    const int a_r = t >> 3;            // 0..31
    const int a_c = (t & 7) * 4;       // 0..28
    const int b_r = t >> 4;            // 0..15
    const int b_c = (t & 15) * 4;      // 0..60
    const int tx  = (t & 15) * 4;      // n local
    const int ty  = (t >> 4) * 2;      // m local, 0..30

    float acc[2][4] = {};
    const int k0 = kz * 320;

    for (int kk = k0; kk < k0 + 320; kk += 32) {
        float4 av = *(const float4*)&X[(m0 + a_r) * FDIM + kk + a_c];
        As[a_c + 0][a_r] = av.x;
        As[a_c + 1][a_r] = av.y;
        As[a_c + 2][a_r] = av.z;
        As[a_c + 3][a_r] = av.w;
        *(float4*)&Bs[b_r][b_c]      = *(const float4*)&W[(kk + b_r) * HDIM + n0 + b_c];
        *(float4*)&Bs[b_r + 16][b_c] = *(const float4*)&W[(kk + b_r + 16) * HDIM + n0 + b_c];
        __syncthreads();
#pragma unroll
        for (int k = 0; k < 32; k++) {
            float2 a = *(const float2*)&As[k][ty];
            float4 b = *(const float4*)&Bs[k][tx];
            acc[0][0] = fmaf(a.x, b.x, acc[0][0]);
            acc[0][1] = fmaf(a.x, b.y, acc[0][1]);
            acc[0][2] = fmaf(a.x, b.z, acc[0][2]);
            acc[0][3] = fmaf(a.x, b.w, acc[0][3]);
            acc[1][0] = fmaf(a.y, b.x, acc[1][0]);
            acc[1][1] = fmaf(a.y, b.y, acc[1][1]);
            acc[1][2] = fmaf(a.y, b.z, acc[1][2]);
            acc[1][3] = fmaf(a.y, b.w, acc[1][3]);
        }
        __syncthreads();
    }
#pragma unroll
    for (int r = 0; r < 2; r++) {
        float4 v = make_float4(acc[r][0], acc[r][1], acc[r][2], acc[r][3]);
        *(float4*)&O[(m0 + ty + r) * HDIM + n0 + tx] = v;
    }
}

// ---------------- Kernel 2: per-row epilogue, one wave per row ----------------
// grid 384, block 256 (4 waves = 4 rows)
__global__ __launch_bounds__(256) void k_row(const float* __restrict__ h1a,
                                             const float* __restrict__ h1b,
                                             const float* __restrict__ b1,
                                             const float* __restrict__ gam,
                                             const float* __restrict__ bet,
                                             const float* __restrict__ rmean,
                                             const float* __restrict__ rvar,
                                             const float* __restrict__ W2,
                                             const float* __restrict__ b2,
                                             const float* __restrict__ W3,
                                             const float* __restrict__ b3,
                                             const int* __restrict__ seq,
                                             float* __restrict__ out,
                                             float* __restrict__ qc,
                                             int* __restrict__ flags) {
    __shared__ float sh[4][130];
    const int t = threadIdx.x, w = t >> 6, lane = t & 63;
    const int row = blockIdx.x * 4 + w;
#pragma unroll
    for (int c = lane; c < 128; c += 64) {
        float v = h1a[row * HDIM + c] + h1b[row * HDIM + c] + b1[c];
        v = fmaxf(v, 0.0f);
        v = gam[c] * (v - rmean[c]) / sqrtf(rvar[c] + 1e-5f) + bet[c];
        sh[w][c] = v;
    }
    __syncthreads();
    float acc = b2[lane];
#pragma unroll 8
    for (int c = 0; c < 128; c++)
        acc = fmaf(sh[w][c], W2[c * 64 + lane], acc);
    float h2 = fmaxf(acc, 0.0f);
    float x0 = h2 * W3[lane * 3 + 0];
    float x1 = h2 * W3[lane * 3 + 1];
    float x2 = h2 * W3[lane * 3 + 2];
#pragma unroll
    for (int o = 32; o > 0; o >>= 1) {
        x0 += __shfl_xor(x0, o, 64);
        x1 += __shfl_xor(x1, o, 64);
        x2 += __shfl_xor(x2, o, 64);
    }
    if (lane == 0) {
        float l0 = x0 + b3[0], l1 = x1 + b3[1], l2 = x2 + b3[2];
        float m = fmaxf(l0, fmaxf(l1, l2));
        float e0 = expf(l0 - m), e1 = expf(l1 - m), e2 = expf(l2 - m);
        float s = e0 + e1 + e2;
        float pc0 = e0 / s, pc1 = e1 / s, pc2 = e2 / s;
        out[OUT_PC + row * 3 + 0] = pc0;
        out[OUT_PC + row * 3 + 1] = pc1;
        out[OUT_PC + row * 3 + 2] = pc2;
        float net = pc0 - pc1;
        out[OUT_NET + row] = net;
        qc[row] = net;
        flags[row] = (pc0 > pc2 ? 1 : 0) | (pc1 > pc2 ? 2 : 0);
        int sid = seq[row];
        float c0 = (sid == 6 || sid == 8 || sid == 14) ? 1.0f : 0.0f;
        float c1 = (sid == 2 || sid == 3) ? 1.0f : 0.0f;
        out[OUT_TC + row * 3 + 0] = c0;
        out[OUT_TC + row * 3 + 1] = c1;
        out[OUT_TC + row * 3 + 2] = (c0 == 0.0f && c1 == 0.0f) ? 1.0f : 0.0f;
    }
}

// ---------------- Kernel 3: conv stack + zero energy/counter ----------------
// grid 4, block 384
__global__ __launch_bounds__(384) void k_conv(const float* __restrict__ net,
                                              const float* __restrict__ c1w, const float* __restrict__ c1b,
                                              const float* __restrict__ c2w, const float* __restrict__ c2b,
                                              const float* __restrict__ c3w, const float* __restrict__ c3b,
                                              float* __restrict__ out,
                                              unsigned int* __restrict__ cnt) {
    __shared__ float p0[LSEQ + 4];
    __shared__ float p1[16][LSEQ + 2];
    __shared__ float p2[8][LSEQ + 2];
    const int b = blockIdx.x, t = threadIdx.x;
    p0[t + 2] = net[b * LSEQ + t];
    if (t < 2) { p0[t] = 0.0f; p0[LSEQ + 2 + t] = 0.0f; }
    if (t < 16) { p1[t][0] = 0.0f; p1[t][LSEQ + 1] = 0.0f; }
    if (t < 8)  { p2[t][0] = 0.0f; p2[t][LSEQ + 1] = 0.0f; }
    if (b == 0) {
        if (t < 4) out[OUT_EN + t] = 0.0f;
        if (t == 4) *cnt = 0u;
    }
    __syncthreads();
#pragma unroll
    for (int o = 0; o < 16; o++) {
        float acc = c1b[o];
#pragma unroll
        for (int k = 0; k < 5; k++) acc = fmaf(p0[t + k], c1w[o * 5 + k], acc);
        p1[o][t + 1] = fmaxf(acc, 0.0f);
    }
    __syncthreads();
#pragma unroll
    for (int o = 0; o < 8; o++) {
        float acc = c2b[o];
        for (int i = 0; i < 16; i++)
#pragma unroll
            for (int k = 0; k < 3; k++)
                acc = fmaf(p1[i][t + k], c2w[(o * 16 + i) * 3 + k], acc);
        p2[o][t + 1] = fmaxf(acc, 0.0f);
    }
    __syncthreads();
    {
        float acc = c3b[0];
        for (int i = 0; i < 8; i++)
#pragma unroll
            for (int k = 0; k < 3; k++)
                acc = fmaf(p2[i][t + k], c3w[i * 3 + k], acc);
        out[OUT_POT + b * LSEQ + t] = acc;
    }
}

// ---------------- Kernel 4: pair sweep (mask zeros, energy, candidate list) ----------------
// grid 1536 (= b*L+i), block 256
__global__ __launch_bounds__(256) void k_pair(const float* __restrict__ S,
                                              const float* __restrict__ qc,
                                              const int* __restrict__ flags,
                                              float* __restrict__ out,
                                              unsigned int* __restrict__ cnt,
                                              unsigned int* __restrict__ list,
                                              unsigned int cap) {
    __shared__ float sx[LSEQ], sy[LSEQ], sz[LSEQ], sq[LSEQ];
    __shared__ int sf[LSEQ];
    __shared__ float red[4];
    const int row = blockIdx.x;
    const int b = row / LSEQ;
    const int i = row - b * LSEQ;
    const int t = threadIdx.x;
    for (int j = t; j < LSEQ; j += 256) {
        int g = b * LSEQ + j;
        sx[j] = S[g * 3 + 0];
        sy[j] = S[g * 3 + 1];
        sz[j] = S[g * 3 + 2];
        sq[j] = qc[g];
        sf[j] = flags[g];
    }
    __syncthreads();
    const float six = sx[i], siy = sy[i], siz = sz[i], qi = sq[i];
    const bool posi = (sf[i] & 1) != 0;
    const int lane = t & 63;
    float esum = 0.0f;
    float* mrow = out + OUT_MASK + (long)row * LSEQ;
    for (int j = t; j < LSEQ; j += 256) {
        float dx = __fsub_rn(six, sx[j]);
        float dy = __fsub_rn(siy, sy[j]);
        float dz = __fsub_rn(siz, sz[j]);
        float d2 = __fadd_rn(__fadd_rn(__fmul_rn(dx, dx), __fmul_rn(dy, dy)), __fmul_rn(dz, dz));
        d2 = __fadd_rn(d2, 1e-12f);
        float D = __fsqrt_rn(d2);
        mrow[j] = 0.0f;
        if (j > i && D < 15.0f && D > 0.0f) {
            float num = __fmul_rn(__fmul_rn(332.0f, qi), sq[j]);
            float den = __fmul_rn(__fmul_rn(20.0f, D), D);
            esum += __fdiv_rn(num, den);
        }
        bool cand = posi && ((sf[j] & 2) != 0) && (D < 4.0f);
        unsigned long long mball = __ballot(cand);
        int nc = __popcll(mball);
        unsigned int base = 0;
        if (lane == 0 && nc > 0) base = atomicAdd(cnt, (unsigned int)nc);
        base = __shfl(base, 0, 64);
        if (cand) {
            int off = __popcll(mball & ((1ull << lane) - 1ull));
            unsigned int p = base + (unsigned int)off;
            if (p < cap) list[p] = ((unsigned int)row << 9) | (unsigned int)j;
        }
    }
    for (int o = 32; o > 0; o >>= 1) esum += __shfl_xor(esum, o, 64);
    if (lane == 0) red[t >> 6] = esum;
    __syncthreads();
    if (t == 0) {
        float s = red[0] + red[1] + red[2] + red[3];
        atomicAdd(&out[OUT_EN + b], s);
    }
}

// ---------------- Kernel 5: candidate MLP -> mask scatter ----------------
// grid 192, block 256 (one wave per candidate, strided). sW2 in LDS; h in regs,
// broadcast via readlane; fi/fj are split-K partial sums (a+b).
__global__ __launch_bounds__(256) void k_cand(const float* __restrict__ S,
                                              const float* __restrict__ fiA,
                                              const float* __restrict__ fiB,
                                              const float* __restrict__ fjA,
                                              const float* __restrict__ fjB,
                                              const float* __restrict__ sW1,
                                              const float* __restrict__ sb1,
                                              const float* __restrict__ sW2,
                                              const float* __restrict__ sb2,
                                              const float* __restrict__ sW3,
                                              const float* __restrict__ sb3,
                                              const unsigned int* __restrict__ cnt,
                                              const unsigned int* __restrict__ list,
                                              float* __restrict__ out,
                                              unsigned int cap) {
    unsigned int n = *cnt;
    if (n > cap) n = cap;
    if (blockIdx.x * 4 >= n) return;   // block-uniform early out (before barrier)

    __shared__ float w2s[128 * 64];    // 32 KB, [cc][l]: 2 lanes/bank = free
    const int t = threadIdx.x;
    for (int idx = t; idx < 2048; idx += 256)
        ((float4*)w2s)[idx] = ((const float4*)sW2)[idx];

    const int lane = t & 63;
    const int w = t >> 6;
    const float* dvec = sW1 + 1280 * 128;
    const float dv0 = dvec[lane],    dv1 = dvec[lane + 64];
    const float sb0 = sb1[lane],     sb1v = sb1[lane + 64];
    const float w3  = sW3[lane];
    const float b2v = sb2[lane];
    const float b3v = sb3[0];
    float* mask = out + OUT_MASK;
    __syncthreads();

    const int gw = blockIdx.x * 4 + w;
    const int nw = gridDim.x * 4;
    for (unsigned int c = (unsigned int)gw; c < n; c += (unsigned int)nw) {
        unsigned int v = list[c];
        int row = (int)(v >> 9);
        int j = (int)(v & 511u);
        int i = row % LSEQ;
        int col = row - i + j;
        float dx = __fsub_rn(S[row * 3 + 0], S[col * 3 + 0]);
        float dy = __fsub_rn(S[row * 3 + 1], S[col * 3 + 1]);
        float dz = __fsub_rn(S[row * 3 + 2], S[col * 3 + 2]);
        float d2 = __fadd_rn(__fadd_rn(__fmul_rn(dx, dx), __fmul_rn(dy, dy)), __fmul_rn(dz, dz));
        d2 = __fadd_rn(d2, 1e-12f);
        float D = __fsqrt_rn(d2);
        float fi0 = fiA[(long)row * 128 + lane]      + fiB[(long)row * 128 + lane];
        float fi1 = fiA[(long)row * 128 + 64 + lane] + fiB[(long)row * 128 + 64 + lane];
        float fj0 = fjA[(long)col * 128 + lane]      + fjB[(long)col * 128 + lane];
        float fj1 = fjA[(long)col * 128 + 64 + lane] + fjB[(long)col * 128 + 64 + lane];
        float h0 = fmaxf(fi0 + fj0 + D * dv0 + sb0, 0.0f);
        float h1 = fmaxf(fi1 + fj1 + D * dv1 + sb1v, 0.0f);
        float acc0 = 0.0f, acc1 = 0.0f;
#pragma unroll
        for (int cc = 0; cc < 64; cc++) {
            float hv0 = __uint_as_float(__builtin_amdgcn_readlane(__float_as_uint(h0), cc));
            float hv1 = __uint_as_float(__builtin_amdgcn_readlane(__float_as_uint(h1), cc));
            acc0 = fmaf(hv0, w2s[cc * 64 + lane], acc0);
            acc1 = fmaf(hv1, w2s[(cc + 64) * 64 + lane], acc1);
        }
        float x = fmaxf(acc0 + acc1 + b2v, 0.0f) * w3;
        for (int o = 32; o > 0; o >>= 1) x += __shfl_xor(x, o, 64);
        if (lane == 0 && (x + b3v) > 0.0f) {
            mask[(long)row * LSEQ + j] = 1.0f;
            mask[(long)col * LSEQ + i] = 1.0f;
        }
    }
}

extern "C" void kernel_launch(void* const* d_in, const int* in_sizes, int n_in,
                              void* d_out, int out_size, void* d_ws, size_t ws_size,
                              hipStream_t stream) {
    const float* X     = (const float*)d_in[0];
    const int*   seq   = (const int*)d_in[1];
    const float* S     = (const float*)d_in[2];
    const float* W1    = (const float*)d_in[3];
    const float* b1    = (const float*)d_in[4];
    const float* gam   = (const float*)d_in[5];
    const float* bet   = (const float*)d_in[6];
    const float* rmean = (const float*)d_in[7];
    const float* rvar  = (const float*)d_in[8];
    const float* W2    = (const float*)d_in[9];
    const float* b2    = (const float*)d_in[10];
    const float* W3    = (const float*)d_in[11];
    const float* b3    = (const float*)d_in[12];
    const float* sW1   = (const float*)d_in[13];
    const float* sb1   = (const float*)d_in[14];
    const float* sW2   = (const float*)d_in[15];
    const float* sb2   = (const float*)d_in[16];
    const float* sW3   = (const float*)d_in[17];
    const float* sb3   = (const float*)d_in[18];
    const float* c1w   = (const float*)d_in[19];
    const float* c1b   = (const float*)d_in[20];
    const float* c2w   = (const float*)d_in[21];
    const float* c2b   = (const float*)d_in[22];
    const float* c3w   = (const float*)d_in[23];
    const float* c3b   = (const float*)d_in[24];

    float* out = (float*)d_out;
    float* ws  = (float*)d_ws;
    unsigned int* cnt  = (unsigned int*)(ws + WS_CNT);
    unsigned int* list = (unsigned int*)(ws + WS_LIST);
    int* flags = (int*)(ws + WS_FLAG);

    unsigned int cap = 0;
    size_t ws_floats = ws_size / 4;
    if (ws_floats > (size_t)WS_LIST) {
        size_t room = ws_floats - WS_LIST;
        cap = (unsigned int)(room < CAPMAX ? room : CAPMAX);
    }

    hipLaunchKernelGGL(k_gemm, dim3(48, 6, 2), dim3(256), 0, stream, X, W1, sW1, ws);
    hipLaunchKernelGGL(k_row, dim3(384), dim3(256), 0, stream,
                       ws + WS_H1, ws + WS_H1 + PART, b1, gam, bet, rmean, rvar,
                       W2, b2, W3, b3, seq, out, ws + WS_QC, flags);
    hipLaunchKernelGGL(k_conv, dim3(4), dim3(384), 0, stream,
                       out + OUT_NET, c1w, c1b, c2w, c2b, c3w, c3b, out, cnt);
    hipLaunchKernelGGL(k_pair, dim3(1536), dim3(256), 0, stream,
                       S, ws + WS_QC, flags, out, cnt, list, cap);
    hipLaunchKernelGGL(k_cand, dim3(192), dim3(256), 0, stream,
                       S, ws + WS_FI, ws + WS_FI + PART, ws + WS_FJ, ws + WS_FJ + PART,
                       sW1, sb1, sW2, sb2, sW3, sb3, cnt, list, out, cap);
}

// Round 4
// 171.473 us; speedup vs baseline: 1.4097x; 1.1079x over previous
//
#include <hip/hip_runtime.h>

#define LSEQ 384
#define NROWS 1536      // B*L
#define FDIM 640
#define HDIM 128
#define PART 196608     // 1536*128

// ws layout (float indices): fi/fj split-K partials + qc + flags
#define WS_FI   0              // parts at 0, 196608
#define WS_FJ   393216         // parts at 393216, 589824
#define WS_QC   786432
#define WS_FLAG 787968         // int[1536]

// out layout (float indices)
#define OUT_PC    0
#define OUT_TC    4608
#define OUT_NET   9216
#define OUT_POT   10752
#define OUT_MASK  12288
#define OUT_EN    602112

// =========== Kernel 1: projections + row epilogue ===========
// grid 480: blocks 0..95  -> H1 rows (BM=16, BN=128, full K) + BN/W2/W3/softmax epilogue
//           blocks 96..479 -> fi/fj tiles (BM=32, BN=64, split-K=2), as R3 k_gemm
__global__ __launch_bounds__(256) void k1(const float* __restrict__ X,
                                          const float* __restrict__ W1,
                                          const float* __restrict__ sW1,
                                          const float* __restrict__ b1,
                                          const float* __restrict__ gam,
                                          const float* __restrict__ bet,
                                          const float* __restrict__ rmean,
                                          const float* __restrict__ rvar,
                                          const float* __restrict__ W2,
                                          const float* __restrict__ b2,
                                          const float* __restrict__ W3,
                                          const float* __restrict__ b3,
                                          const int* __restrict__ seq,
                                          float* __restrict__ out,
                                          float* __restrict__ ws) {
    __shared__ char smem[27648];
    const int t = threadIdx.x;
    const int blk = blockIdx.x;

    if (blk == 0 && t < 4) out[OUT_EN + t] = 0.0f;   // energy zero (consumed in k2)

    if (blk < 96) {
        // ---- type A: H1 + epilogue ----
        float* As = (float*)smem;                    // [32][18]
        float* Bs = (float*)(smem + 2304);           // [32][128]
        float* hs = (float*)(smem + 18688);          // [16][132]
        const int m0 = blk * 16;
        const int tx = (t & 31) * 4;                 // n 0..124
        const int ty = (t >> 5) * 2;                 // m 0..14
        float acc[2][4] = {};
        for (int kk = 0; kk < FDIM; kk += 32) {
            if (t < 128) {
                int a_r = t >> 3, a_c = (t & 7) * 4;
                float4 av = *(const float4*)&X[(m0 + a_r) * FDIM + kk + a_c];
                As[(a_c + 0) * 18 + a_r] = av.x;
                As[(a_c + 1) * 18 + a_r] = av.y;
                As[(a_c + 2) * 18 + a_r] = av.z;
                As[(a_c + 3) * 18 + a_r] = av.w;
            }
#pragma unroll
            for (int q = 0; q < 4; q++) {
                int idx = t + 256 * q;
                int r = idx >> 5, c4 = (idx & 31) * 4;
                *(float4*)&Bs[r * 128 + c4] = *(const float4*)&W1[(kk + r) * HDIM + c4];
            }
            __syncthreads();
#pragma unroll
            for (int k = 0; k < 32; k++) {
                float2 a = *(const float2*)&As[k * 18 + ty];
                float4 b = *(const float4*)&Bs[k * 128 + tx];
                acc[0][0] = fmaf(a.x, b.x, acc[0][0]);
                acc[0][1] = fmaf(a.x, b.y, acc[0][1]);
                acc[0][2] = fmaf(a.x, b.z, acc[0][2]);
                acc[0][3] = fmaf(a.x, b.w, acc[0][3]);
                acc[1][0] = fmaf(a.y, b.x, acc[1][0]);
                acc[1][1] = fmaf(a.y, b.y, acc[1][1]);
                acc[1][2] = fmaf(a.y, b.z, acc[1][2]);
                acc[1][3] = fmaf(a.y, b.w, acc[1][3]);
            }
            __syncthreads();
        }
        // BN epilogue -> hs
        {
            float4 b1v = *(const float4*)&b1[tx];
            float4 g4  = *(const float4*)&gam[tx];
            float4 be4 = *(const float4*)&bet[tx];
            float4 rm4 = *(const float4*)&rmean[tx];
            float4 rv4 = *(const float4*)&rvar[tx];
            float rs0 = 1.0f / sqrtf(rv4.x + 1e-5f);
            float rs1 = 1.0f / sqrtf(rv4.y + 1e-5f);
            float rs2 = 1.0f / sqrtf(rv4.z + 1e-5f);
            float rs3 = 1.0f / sqrtf(rv4.w + 1e-5f);
#pragma unroll
            for (int r = 0; r < 2; r++) {
                float v0 = g4.x * (fmaxf(acc[r][0] + b1v.x, 0.0f) - rm4.x) * rs0 + be4.x;
                float v1 = g4.y * (fmaxf(acc[r][1] + b1v.y, 0.0f) - rm4.y) * rs1 + be4.y;
                float v2 = g4.z * (fmaxf(acc[r][2] + b1v.z, 0.0f) - rm4.z) * rs2 + be4.z;
                float v3 = g4.w * (fmaxf(acc[r][3] + b1v.w, 0.0f) - rm4.w) * rs3 + be4.w;
                *(float4*)&hs[(ty + r) * 132 + tx] = make_float4(v0, v1, v2, v3);
            }
        }
        __syncthreads();
        // wave phase: 4 rows per wave
        const int w = t >> 6, lane = t & 63;
        float h0r[4], h1r[4], acc2[4];
#pragma unroll
        for (int r = 0; r < 4; r++) {
            h0r[r] = hs[(w * 4 + r) * 132 + lane];
            h1r[r] = hs[(w * 4 + r) * 132 + 64 + lane];
            acc2[r] = b2[lane];
        }
#pragma unroll
        for (int cc = 0; cc < 64; cc++) {
            float wv0 = W2[cc * 64 + lane];
            float wv1 = W2[(cc + 64) * 64 + lane];
#pragma unroll
            for (int r = 0; r < 4; r++) {
                float hv0 = __uint_as_float(__builtin_amdgcn_readlane(__float_as_uint(h0r[r]), cc));
                float hv1 = __uint_as_float(__builtin_amdgcn_readlane(__float_as_uint(h1r[r]), cc));
                acc2[r] = fmaf(hv0, wv0, acc2[r]);
                acc2[r] = fmaf(hv1, wv1, acc2[r]);
            }
        }
        float w30 = W3[lane * 3 + 0], w31 = W3[lane * 3 + 1], w32 = W3[lane * 3 + 2];
#pragma unroll
        for (int r = 0; r < 4; r++) {
            float h2 = fmaxf(acc2[r], 0.0f);
            float x0 = h2 * w30, x1 = h2 * w31, x2 = h2 * w32;
#pragma unroll
            for (int o = 32; o > 0; o >>= 1) {
                x0 += __shfl_xor(x0, o, 64);
                x1 += __shfl_xor(x1, o, 64);
                x2 += __shfl_xor(x2, o, 64);
            }
            if (lane == 0) {
                int row = m0 + w * 4 + r;
                float l0 = x0 + b3[0], l1 = x1 + b3[1], l2 = x2 + b3[2];
                float m = fmaxf(l0, fmaxf(l1, l2));
                float e0 = expf(l0 - m), e1 = expf(l1 - m), e2 = expf(l2 - m);
                float s = e0 + e1 + e2;
                float pc0 = e0 / s, pc1 = e1 / s, pc2 = e2 / s;
                out[OUT_PC + row * 3 + 0] = pc0;
                out[OUT_PC + row * 3 + 1] = pc1;
                out[OUT_PC + row * 3 + 2] = pc2;
                float net = pc0 - pc1;
                out[OUT_NET + row] = net;
                ws[WS_QC + row] = net;
                ((int*)(ws + WS_FLAG))[row] = (pc0 > pc2 ? 1 : 0) | (pc1 > pc2 ? 2 : 0);
                int sid = seq[row];
                float c0 = (sid == 6 || sid == 8 || sid == 14) ? 1.0f : 0.0f;
                float c1 = (sid == 2 || sid == 3) ? 1.0f : 0.0f;
                out[OUT_TC + row * 3 + 0] = c0;
                out[OUT_TC + row * 3 + 1] = c1;
                out[OUT_TC + row * 3 + 2] = (c0 == 0.0f && c1 == 0.0f) ? 1.0f : 0.0f;
            }
        }
    } else {
        // ---- type B: fi/fj split-K tiles ----
        float* As = (float*)smem;                    // [32][34]
        float* Bs = (float*)(smem + 4352);           // [32][64]
        const int bi = blk - 96;
        const int kz = bi & 1, half = (bi >> 1) & 1, mat = (bi >> 2) & 1, mt = bi >> 3;
        const int m0 = mt * 32, n0 = half * 64;
        const float* W = sW1 + mat * 640 * 128;
        float* O = ws + (mat == 0 ? WS_FI : WS_FJ) + kz * PART;
        const int a_r = t >> 3, a_c = (t & 7) * 4;
        const int b_r = t >> 4, b_c = (t & 15) * 4;
        const int tx = (t & 15) * 4, ty = (t >> 4) * 2;
        float acc[2][4] = {};
        const int k0 = kz * 320;
        for (int kk = k0; kk < k0 + 320; kk += 32) {
            float4 av = *(const float4*)&X[(m0 + a_r) * FDIM + kk + a_c];
            As[(a_c + 0) * 34 + a_r] = av.x;
            As[(a_c + 1) * 34 + a_r] = av.y;
            As[(a_c + 2) * 34 + a_r] = av.z;
            As[(a_c + 3) * 34 + a_r] = av.w;
            *(float4*)&Bs[b_r * 64 + b_c]        = *(const float4*)&W[(kk + b_r) * HDIM + n0 + b_c];
            *(float4*)&Bs[(b_r + 16) * 64 + b_c] = *(const float4*)&W[(kk + b_r + 16) * HDIM + n0 + b_c];
            __syncthreads();
#pragma unroll
            for (int k = 0; k < 32; k++) {
                float2 a = *(const float2*)&As[k * 34 + ty];
                float4 b = *(const float4*)&Bs[k * 64 + tx];
                acc[0][0] = fmaf(a.x, b.x, acc[0][0]);
                acc[0][1] = fmaf(a.x, b.y, acc[0][1]);
                acc[0][2] = fmaf(a.x, b.z, acc[0][2]);
                acc[0][3] = fmaf(a.x, b.w, acc[0][3]);
                acc[1][0] = fmaf(a.y, b.x, acc[1][0]);
                acc[1][1] = fmaf(a.y, b.y, acc[1][1]);
                acc[1][2] = fmaf(a.y, b.z, acc[1][2]);
                acc[1][3] = fmaf(a.y, b.w, acc[1][3]);
            }
            __syncthreads();
        }
#pragma unroll
        for (int r = 0; r < 2; r++) {
            float4 v = make_float4(acc[r][0], acc[r][1], acc[r][2], acc[r][3]);
            *(float4*)&O[(m0 + ty + r) * HDIM + n0 + tx] = v;
        }
    }
}

// =========== Kernel 2: conv + pair sweep + inline candidate MLP ===========
// grid 1540: blocks 0..3 conv (one per batch); blocks 4..1539 one mask row each.
__device__ __forceinline__ float mlp_eval(const float* __restrict__ fiA, const float* __restrict__ fiB,
                                          const float* __restrict__ fjA, const float* __restrict__ fjB,
                                          int gi, int gj, float D,
                                          float dv0, float dv1, float sb0, float sb1v,
                                          float b2v, float w3l, const float* w2s, int lane) {
    float fi0 = fiA[gi * 128 + lane]      + fiB[gi * 128 + lane];
    float fi1 = fiA[gi * 128 + 64 + lane] + fiB[gi * 128 + 64 + lane];
    float fj0 = fjA[gj * 128 + lane]      + fjB[gj * 128 + lane];
    float fj1 = fjA[gj * 128 + 64 + lane] + fjB[gj * 128 + 64 + lane];
    float h0 = fmaxf(fi0 + fj0 + D * dv0 + sb0, 0.0f);
    float h1 = fmaxf(fi1 + fj1 + D * dv1 + sb1v, 0.0f);
    float a0 = 0.0f, a1 = 0.0f;
#pragma unroll
    for (int cc = 0; cc < 64; cc++) {
        float hv0 = __uint_as_float(__builtin_amdgcn_readlane(__float_as_uint(h0), cc));
        float hv1 = __uint_as_float(__builtin_amdgcn_readlane(__float_as_uint(h1), cc));
        a0 = fmaf(hv0, w2s[cc * 64 + lane], a0);
        a1 = fmaf(hv1, w2s[(cc + 64) * 64 + lane], a1);
    }
    float x = fmaxf(a0 + a1 + b2v, 0.0f) * w3l;
#pragma unroll
    for (int o = 32; o > 0; o >>= 1) x += __shfl_xor(x, o, 64);
    return x;
}

__global__ __launch_bounds__(256) void k2(const float* __restrict__ S,
                                          const float* __restrict__ ws,
                                          const float* __restrict__ sW1,
                                          const float* __restrict__ sb1,
                                          const float* __restrict__ sW2,
                                          const float* __restrict__ sb2,
                                          const float* __restrict__ sW3,
                                          const float* __restrict__ sb3,
                                          const float* __restrict__ c1w, const float* __restrict__ c1b,
                                          const float* __restrict__ c2w, const float* __restrict__ c2b,
                                          const float* __restrict__ c3w, const float* __restrict__ c3b,
                                          float* __restrict__ out) {
    __shared__ char smem[40960];
    const int t = threadIdx.x;
    const int bi = blockIdx.x;

    if (bi < 4) {
        // ---- conv stack, 256 threads looping over 384 positions ----
        float* p0 = (float*)smem;          // 388
        float* p1 = p0 + 388;              // 16*386
        float* p2 = p1 + 16 * 386;         // 8*386
        const int b = bi;
        for (int j = t; j < LSEQ; j += 256) p0[j + 2] = out[OUT_NET + b * LSEQ + j];
        if (t < 2) { p0[t] = 0.0f; p0[LSEQ + 2 + t] = 0.0f; }
        if (t < 16) { p1[t * 386] = 0.0f; p1[t * 386 + 385] = 0.0f; }
        if (t < 8)  { p2[t * 386] = 0.0f; p2[t * 386 + 385] = 0.0f; }
        __syncthreads();
        for (int pos = t; pos < LSEQ; pos += 256) {
#pragma unroll
            for (int o = 0; o < 16; o++) {
                float acc = c1b[o];
#pragma unroll
                for (int k = 0; k < 5; k++) acc = fmaf(p0[pos + k], c1w[o * 5 + k], acc);
                p1[o * 386 + pos + 1] = fmaxf(acc, 0.0f);
            }
        }
        __syncthreads();
        for (int pos = t; pos < LSEQ; pos += 256) {
#pragma unroll
            for (int o = 0; o < 8; o++) {
                float acc = c2b[o];
                for (int i = 0; i < 16; i++)
#pragma unroll
                    for (int k = 0; k < 3; k++)
                        acc = fmaf(p1[i * 386 + pos + k], c2w[(o * 16 + i) * 3 + k], acc);
                p2[o * 386 + pos + 1] = fmaxf(acc, 0.0f);
            }
        }
        __syncthreads();
        for (int pos = t; pos < LSEQ; pos += 256) {
            float acc = c3b[0];
            for (int i = 0; i < 8; i++)
#pragma unroll
                for (int k = 0; k < 3; k++)
                    acc = fmaf(p2[i * 386 + pos + k], c3w[i * 3 + k], acc);
            out[OUT_POT + b * LSEQ + pos] = acc;
        }
        return;
    }

    // ---- pair row ----
    float* sx = (float*)smem;                       // 384
    float* sy = sx + 384;
    float* sz = sy + 384;
    float* sq = sz + 384;
    unsigned int* clist = (unsigned int*)(sz + 768); // = smem+6144, 384 u32
    unsigned char* sf = (unsigned char*)(smem + 7680); // 384
    float* red = (float*)(smem + 8064);             // 4
    int* cntL = (int*)(smem + 8080);
    float* w2s = (float*)(smem + 8192);             // 128*64

    const float* qc = ws + WS_QC;
    const int* flags = (const int*)(ws + WS_FLAG);
    const float* fiA = ws + WS_FI;
    const float* fiB = ws + WS_FI + PART;
    const float* fjA = ws + WS_FJ;
    const float* fjB = ws + WS_FJ + PART;

    const int row = bi - 4;
    const int b = row / LSEQ;
    const int i = row - b * LSEQ;

    for (int j = t; j < LSEQ; j += 256) {
        int g = b * LSEQ + j;
        sx[j] = S[g * 3 + 0];
        sy[j] = S[g * 3 + 1];
        sz[j] = S[g * 3 + 2];
        sq[j] = qc[g];
        sf[j] = (unsigned char)flags[g];
    }
    if (t == 0) *cntL = 0;
    __syncthreads();

    const float six = sx[i], siy = sy[i], siz = sz[i], qi = sq[i];
    const int fli = sf[i];
    const bool posi = (fli & 1) != 0, negi = (fli & 2) != 0;
    const int lane = t & 63, w = t >> 6;
    float esum = 0.0f;
    float* mrow = out + OUT_MASK + (long)row * LSEQ;

    for (int j = t; j < LSEQ; j += 256) {
        float dx = __fsub_rn(six, sx[j]);
        float dy = __fsub_rn(siy, sy[j]);
        float dz = __fsub_rn(siz, sz[j]);
        float d2 = __fadd_rn(__fadd_rn(__fmul_rn(dx, dx), __fmul_rn(dy, dy)), __fmul_rn(dz, dz));
        d2 = __fadd_rn(d2, 1e-12f);
        float D = __fsqrt_rn(d2);
        mrow[j] = 0.0f;
        if (j > i && D < 15.0f && D > 0.0f) {
            float num = __fmul_rn(__fmul_rn(332.0f, qi), sq[j]);
            float den = __fmul_rn(__fmul_rn(20.0f, D), D);
            esum += __fdiv_rn(num, den);
        }
        int flj = sf[j];
        bool near = (D < 4.0f);
        bool need1 = near && posi && ((flj & 2) != 0);
        bool need2 = near && negi && ((flj & 1) != 0);
        if (need1 || need2) {
            int p = atomicAdd(cntL, 1);
            clist[p] = (unsigned int)j | (need1 ? 512u : 0u) | (need2 ? 1024u : 0u);
        }
    }
#pragma unroll
    for (int o = 32; o > 0; o >>= 1) esum += __shfl_xor(esum, o, 64);
    if (lane == 0) red[w] = esum;
    __syncthreads();
    if (t == 0) {
        float s = red[0] + red[1] + red[2] + red[3];
        atomicAdd(&out[OUT_EN + b], s);
    }

    int nc = *cntL;   // valid: barrier above
    if (nc == 0) return;

    for (int idx = t; idx < 2048; idx += 256)
        ((float4*)w2s)[idx] = ((const float4*)sW2)[idx];
    const float* dvec = sW1 + 1280 * 128;
    const float dv0 = dvec[lane], dv1 = dvec[lane + 64];
    const float sb0 = sb1[lane], sb1v = sb1[lane + 64];
    const float w3l = sW3[lane];
    const float b2v = sb2[lane];
    const float b3v = sb3[0];
    __syncthreads();

    for (int c = w; c < nc; c += 4) {
        unsigned int e = clist[c];
        int j = (int)(e & 511u);
        bool need1 = (e & 512u) != 0, need2 = (e & 1024u) != 0;
        float dx = __fsub_rn(six, sx[j]);
        float dy = __fsub_rn(siy, sy[j]);
        float dz = __fsub_rn(siz, sz[j]);
        float d2 = __fadd_rn(__fadd_rn(__fmul_rn(dx, dx), __fmul_rn(dy, dy)), __fmul_rn(dz, dz));
        d2 = __fadd_rn(d2, 1e-12f);
        float D = __fsqrt_rn(d2);
        int gi = row, gj = b * LSEQ + j;
        bool hit = false;
        if (need1) {
            float x = mlp_eval(fiA, fiB, fjA, fjB, gi, gj, D, dv0, dv1, sb0, sb1v, b2v, w3l, w2s, lane);
            hit = (x + b3v) > 0.0f;
        }
        if (!hit && need2) {
            float x = mlp_eval(fiA, fiB, fjA, fjB, gj, gi, D, dv0, dv1, sb0, sb1v, b2v, w3l, w2s, lane);
            hit = (x + b3v) > 0.0f;
        }
        if (hit && lane == 0) mrow[j] = 1.0f;
    }
}

extern "C" void kernel_launch(void* const* d_in, const int* in_sizes, int n_in,
                              void* d_out, int out_size, void* d_ws, size_t ws_size,
                              hipStream_t stream) {
    const float* X     = (const float*)d_in[0];
    const int*   seq   = (const int*)d_in[1];
    const float* S     = (const float*)d_in[2];
    const float* W1    = (const float*)d_in[3];
    const float* b1    = (const float*)d_in[4];
    const float* gam   = (const float*)d_in[5];
    const float* bet   = (const float*)d_in[6];
    const float* rmean = (const float*)d_in[7];
    const float* rvar  = (const float*)d_in[8];
    const float* W2    = (const float*)d_in[9];
    const float* b2    = (const float*)d_in[10];
    const float* W3    = (const float*)d_in[11];
    const float* b3    = (const float*)d_in[12];
    const float* sW1   = (const float*)d_in[13];
    const float* sb1   = (const float*)d_in[14];
    const float* sW2   = (const float*)d_in[15];
    const float* sb2   = (const float*)d_in[16];
    const float* sW3   = (const float*)d_in[17];
    const float* sb3   = (const float*)d_in[18];
    const float* c1w   = (const float*)d_in[19];
    const float* c1b   = (const float*)d_in[20];
    const float* c2w   = (const float*)d_in[21];
    const float* c2b   = (const float*)d_in[22];
    const float* c3w   = (const float*)d_in[23];
    const float* c3b   = (const float*)d_in[24];

    float* out = (float*)d_out;
    float* ws  = (float*)d_ws;

    hipLaunchKernelGGL(k1, dim3(480), dim3(256), 0, stream,
                       X, W1, sW1, b1, gam, bet, rmean, rvar, W2, b2, W3, b3,
                       seq, out, ws);
    hipLaunchKernelGGL(k2, dim3(1540), dim3(256), 0, stream,
                       S, ws, sW1, sb1, sW2, sb2, sW3, sb3,
                       c1w, c1b, c2w, c2b, c3w, c3b, out);
}

// Round 5
// 155.757 us; speedup vs baseline: 1.5520x; 1.1009x over previous
//
#include <hip/hip_runtime.h>

#define LSEQ 384
#define NROWS 1536      // B*L
#define FDIM 640
#define HDIM 128
#define PART 196608     // 1536*128

// ws layout (float indices)
#define WS_H1P 0                 // 4 x PART (H1 split-K partials)
#define WS_FIP (4*PART)          // 4 x PART
#define WS_FJP (8*PART)          // 4 x PART
#define WS_FI  (12*PART)         // final fi
#define WS_FJ  (13*PART)         // final fj
#define WS_QC  (14*PART)
#define WS_FLAG (WS_QC + NROWS)  // int[1536]

// out layout (float indices)
#define OUT_PC    0
#define OUT_TC    4608
#define OUT_NET   9216
#define OUT_POT   10752
#define OUT_MASK  12288
#define OUT_EN    602112

// =========== Kernel 1: uniform split-K=4 GEMM, double-buffered ===========
// grid (48, 6, 4): m-tile, gy -> mat=gy>>1 (0=H1,1=fi,2=fj), half=gy&1; z=K chunk.
// BM=32, BN=64, BK=32, 256 threads, acc 2x4.
__global__ __launch_bounds__(256) void k_gemm(const float* __restrict__ X,
                                              const float* __restrict__ W1,
                                              const float* __restrict__ sW1,
                                              float* __restrict__ ws,
                                              float* __restrict__ out) {
    __shared__ float As[2 * 32 * 34];   // [buf][k][m], pad 34
    __shared__ float Bs[2 * 32 * 64];   // [buf][k][n]
    const int t = threadIdx.x;
    if (blockIdx.x == 0 && blockIdx.y == 0 && blockIdx.z == 0 && t < 4)
        out[OUT_EN + t] = 0.0f;        // energy zero (k2 atomicAdds later)

    const int m0 = blockIdx.x * 32;
    const int gy = blockIdx.y, kz = blockIdx.z;
    const int mat = gy >> 1, half = gy & 1, n0 = half * 64;
    const float* W = (mat == 0) ? W1 : (mat == 1 ? sW1 : sW1 + 640 * 128);
    float* O = ws + (mat == 0 ? WS_H1P : (mat == 1 ? WS_FIP : WS_FJP)) + kz * PART;

    const int a_r = t >> 3, a_c = (t & 7) * 4;
    const int b_r = t >> 4, b_c = (t & 15) * 4;
    const int tx = (t & 15) * 4, ty = (t >> 4) * 2;
    const int k0 = kz * 160;            // 5 iterations of BK=32

    float acc[2][4] = {};

    // preload tile 0 into regs, store to buf 0
    float4 av  = *(const float4*)&X[(m0 + a_r) * FDIM + k0 + a_c];
    float4 bv0 = *(const float4*)&W[(k0 + b_r) * HDIM + n0 + b_c];
    float4 bv1 = *(const float4*)&W[(k0 + b_r + 16) * HDIM + n0 + b_c];
    As[(a_c + 0) * 34 + a_r] = av.x;
    As[(a_c + 1) * 34 + a_r] = av.y;
    As[(a_c + 2) * 34 + a_r] = av.z;
    As[(a_c + 3) * 34 + a_r] = av.w;
    *(float4*)&Bs[b_r * 64 + b_c]        = bv0;
    *(float4*)&Bs[(b_r + 16) * 64 + b_c] = bv1;
    __syncthreads();

    for (int it = 0; it < 5; it++) {
        const int buf = it & 1;
        if (it < 4) {  // prefetch next tile into regs (overlaps compute)
            const int kk = k0 + (it + 1) * 32;
            av  = *(const float4*)&X[(m0 + a_r) * FDIM + kk + a_c];
            bv0 = *(const float4*)&W[(kk + b_r) * HDIM + n0 + b_c];
            bv1 = *(const float4*)&W[(kk + b_r + 16) * HDIM + n0 + b_c];
        }
        const float* Ab = As + buf * 1088;
        const float* Bb = Bs + buf * 2048;
#pragma unroll
        for (int k = 0; k < 32; k++) {
            float2 a = *(const float2*)&Ab[k * 34 + ty];
            float4 b = *(const float4*)&Bb[k * 64 + tx];
            acc[0][0] = fmaf(a.x, b.x, acc[0][0]);
            acc[0][1] = fmaf(a.x, b.y, acc[0][1]);
            acc[0][2] = fmaf(a.x, b.z, acc[0][2]);
            acc[0][3] = fmaf(a.x, b.w, acc[0][3]);
            acc[1][0] = fmaf(a.y, b.x, acc[1][0]);
            acc[1][1] = fmaf(a.y, b.y, acc[1][1]);
            acc[1][2] = fmaf(a.y, b.z, acc[1][2]);
            acc[1][3] = fmaf(a.y, b.w, acc[1][3]);
        }
        if (it < 4) {
            float* Aw = As + (buf ^ 1) * 1088;
            float* Bw = Bs + (buf ^ 1) * 2048;
            Aw[(a_c + 0) * 34 + a_r] = av.x;
            Aw[(a_c + 1) * 34 + a_r] = av.y;
            Aw[(a_c + 2) * 34 + a_r] = av.z;
            Aw[(a_c + 3) * 34 + a_r] = av.w;
            *(float4*)&Bw[b_r * 64 + b_c]        = bv0;
            *(float4*)&Bw[(b_r + 16) * 64 + b_c] = bv1;
            __syncthreads();
        }
    }
#pragma unroll
    for (int r = 0; r < 2; r++) {
        float4 v = make_float4(acc[r][0], acc[r][1], acc[r][2], acc[r][3]);
        *(float4*)&O[(m0 + ty + r) * HDIM + n0 + tx] = v;
    }
}

// =========== Kernel 2: partial reduce + row epilogue ===========
// grid 384, block 256: one wave per row. Reduces 4 H1 partials -> BN -> W2
// (readlane) -> W3 -> softmax; also collapses fi/fj partials into final arrays.
__global__ __launch_bounds__(256) void k_row(float* __restrict__ ws,
                                             const float* __restrict__ b1,
                                             const float* __restrict__ gam,
                                             const float* __restrict__ bet,
                                             const float* __restrict__ rmean,
                                             const float* __restrict__ rvar,
                                             const float* __restrict__ W2,
                                             const float* __restrict__ b2,
                                             const float* __restrict__ W3,
                                             const float* __restrict__ b3,
                                             const int* __restrict__ seq,
                                             float* __restrict__ out) {
    const int t = threadIdx.x, w = t >> 6, lane = t & 63;
    const int row = blockIdx.x * 4 + w;
    const long base = (long)row * 128;
    const float* h1p = ws + WS_H1P;
    const float* fip = ws + WS_FIP;
    const float* fjp = ws + WS_FJP;

    // fi/fj partial collapse (2 cols per lane)
    {
        float fi0 = fip[base + lane] + fip[PART + base + lane]
                  + fip[2 * PART + base + lane] + fip[3 * PART + base + lane];
        float fi1 = fip[base + 64 + lane] + fip[PART + base + 64 + lane]
                  + fip[2 * PART + base + 64 + lane] + fip[3 * PART + base + 64 + lane];
        float fj0 = fjp[base + lane] + fjp[PART + base + lane]
                  + fjp[2 * PART + base + lane] + fjp[3 * PART + base + lane];
        float fj1 = fjp[base + 64 + lane] + fjp[PART + base + 64 + lane]
                  + fjp[2 * PART + base + 64 + lane] + fjp[3 * PART + base + 64 + lane];
        ws[WS_FI + base + lane]      = fi0;
        ws[WS_FI + base + 64 + lane] = fi1;
        ws[WS_FJ + base + lane]      = fj0;
        ws[WS_FJ + base + 64 + lane] = fj1;
    }

    // H1 reduce + bias/relu/BN
    float h0 = h1p[base + lane] + h1p[PART + base + lane]
             + h1p[2 * PART + base + lane] + h1p[3 * PART + base + lane];
    float h1 = h1p[base + 64 + lane] + h1p[PART + base + 64 + lane]
             + h1p[2 * PART + base + 64 + lane] + h1p[3 * PART + base + 64 + lane];
    h0 = fmaxf(h0 + b1[lane], 0.0f);
    h1 = fmaxf(h1 + b1[64 + lane], 0.0f);
    h0 = gam[lane]      * (h0 - rmean[lane])      / sqrtf(rvar[lane] + 1e-5f)      + bet[lane];
    h1 = gam[64 + lane] * (h1 - rmean[64 + lane]) / sqrtf(rvar[64 + lane] + 1e-5f) + bet[64 + lane];

    // W2: out channel = lane; inputs broadcast via readlane
    float acc = b2[lane];
#pragma unroll
    for (int cc = 0; cc < 64; cc++) {
        float wv0 = W2[cc * 64 + lane];
        float wv1 = W2[(cc + 64) * 64 + lane];
        float hv0 = __uint_as_float(__builtin_amdgcn_readlane(__float_as_uint(h0), cc));
        float hv1 = __uint_as_float(__builtin_amdgcn_readlane(__float_as_uint(h1), cc));
        acc = fmaf(hv0, wv0, acc);
        acc = fmaf(hv1, wv1, acc);
    }
    float h2 = fmaxf(acc, 0.0f);
    float x0 = h2 * W3[lane * 3 + 0];
    float x1 = h2 * W3[lane * 3 + 1];
    float x2 = h2 * W3[lane * 3 + 2];
#pragma unroll
    for (int o = 32; o > 0; o >>= 1) {
        x0 += __shfl_xor(x0, o, 64);
        x1 += __shfl_xor(x1, o, 64);
        x2 += __shfl_xor(x2, o, 64);
    }
    if (lane == 0) {
        float l0 = x0 + b3[0], l1 = x1 + b3[1], l2 = x2 + b3[2];
        float m = fmaxf(l0, fmaxf(l1, l2));
        float e0 = expf(l0 - m), e1 = expf(l1 - m), e2 = expf(l2 - m);
        float s = e0 + e1 + e2;
        float pc0 = e0 / s, pc1 = e1 / s, pc2 = e2 / s;
        out[OUT_PC + row * 3 + 0] = pc0;
        out[OUT_PC + row * 3 + 1] = pc1;
        out[OUT_PC + row * 3 + 2] = pc2;
        float net = pc0 - pc1;
        out[OUT_NET + row] = net;
        ws[WS_QC + row] = net;
        ((int*)(ws + WS_FLAG))[row] = (pc0 > pc2 ? 1 : 0) | (pc1 > pc2 ? 2 : 0);
        int sid = seq[row];
        float c0 = (sid == 6 || sid == 8 || sid == 14) ? 1.0f : 0.0f;
        float c1 = (sid == 2 || sid == 3) ? 1.0f : 0.0f;
        out[OUT_TC + row * 3 + 0] = c0;
        out[OUT_TC + row * 3 + 1] = c1;
        out[OUT_TC + row * 3 + 2] = (c0 == 0.0f && c1 == 0.0f) ? 1.0f : 0.0f;
    }
}

// =========== Kernel 3: conv + pair sweep + inline candidate MLP ===========
__device__ __forceinline__ float mlp_eval(const float* __restrict__ fi, const float* __restrict__ fj,
                                          int gi, int gj, float D,
                                          float dv0, float dv1, float sb0, float sb1v,
                                          float b2v, float w3l, const float* w2s, int lane) {
    float fi0 = fi[(long)gi * 128 + lane];
    float fi1 = fi[(long)gi * 128 + 64 + lane];
    float fj0 = fj[(long)gj * 128 + lane];
    float fj1 = fj[(long)gj * 128 + 64 + lane];
    float h0 = fmaxf(fi0 + fj0 + D * dv0 + sb0, 0.0f);
    float h1 = fmaxf(fi1 + fj1 + D * dv1 + sb1v, 0.0f);
    float a0 = 0.0f, a1 = 0.0f;
#pragma unroll
    for (int cc = 0; cc < 64; cc++) {
        float hv0 = __uint_as_float(__builtin_amdgcn_readlane(__float_as_uint(h0), cc));
        float hv1 = __uint_as_float(__builtin_amdgcn_readlane(__float_as_uint(h1), cc));
        a0 = fmaf(hv0, w2s[cc * 64 + lane], a0);
        a1 = fmaf(hv1, w2s[(cc + 64) * 64 + lane], a1);
    }
    float x = fmaxf(a0 + a1 + b2v, 0.0f) * w3l;
#pragma unroll
    for (int o = 32; o > 0; o >>= 1) x += __shfl_xor(x, o, 64);
    return x;
}

__global__ __launch_bounds__(256) void k2(const float* __restrict__ S,
                                          const float* __restrict__ ws,
                                          const float* __restrict__ sW1,
                                          const float* __restrict__ sb1,
                                          const float* __restrict__ sW2,
                                          const float* __restrict__ sb2,
                                          const float* __restrict__ sW3,
                                          const float* __restrict__ sb3,
                                          const float* __restrict__ c1w, const float* __restrict__ c1b,
                                          const float* __restrict__ c2w, const float* __restrict__ c2b,
                                          const float* __restrict__ c3w, const float* __restrict__ c3b,
                                          float* __restrict__ out) {
    __shared__ char smem[40960];
    const int t = threadIdx.x;
    const int bi = blockIdx.x;

    if (bi < 4) {
        float* p0 = (float*)smem;
        float* p1 = p0 + 388;
        float* p2 = p1 + 16 * 386;
        const int b = bi;
        for (int j = t; j < LSEQ; j += 256) p0[j + 2] = out[OUT_NET + b * LSEQ + j];
        if (t < 2) { p0[t] = 0.0f; p0[LSEQ + 2 + t] = 0.0f; }
        if (t < 16) { p1[t * 386] = 0.0f; p1[t * 386 + 385] = 0.0f; }
        if (t < 8)  { p2[t * 386] = 0.0f; p2[t * 386 + 385] = 0.0f; }
        __syncthreads();
        for (int pos = t; pos < LSEQ; pos += 256) {
#pragma unroll
            for (int o = 0; o < 16; o++) {
                float acc = c1b[o];
#pragma unroll
                for (int k = 0; k < 5; k++) acc = fmaf(p0[pos + k], c1w[o * 5 + k], acc);
                p1[o * 386 + pos + 1] = fmaxf(acc, 0.0f);
            }
        }
        __syncthreads();
        for (int pos = t; pos < LSEQ; pos += 256) {
#pragma unroll
            for (int o = 0; o < 8; o++) {
                float acc = c2b[o];
                for (int i = 0; i < 16; i++)
#pragma unroll
                    for (int k = 0; k < 3; k++)
                        acc = fmaf(p1[i * 386 + pos + k], c2w[(o * 16 + i) * 3 + k], acc);
                p2[o * 386 + pos + 1] = fmaxf(acc, 0.0f);
            }
        }
        __syncthreads();
        for (int pos = t; pos < LSEQ; pos += 256) {
            float acc = c3b[0];
            for (int i = 0; i < 8; i++)
#pragma unroll
                for (int k = 0; k < 3; k++)
                    acc = fmaf(p2[i * 386 + pos + k], c3w[i * 3 + k], acc);
            out[OUT_POT + b * LSEQ + pos] = acc;
        }
        return;
    }

    float* sx = (float*)smem;
    float* sy = sx + 384;
    float* sz = sy + 384;
    float* sq = sz + 384;
    unsigned int* clist = (unsigned int*)(sz + 768);
    unsigned char* sf = (unsigned char*)(smem + 7680);
    float* red = (float*)(smem + 8064);
    int* cntL = (int*)(smem + 8080);
    float* w2s = (float*)(smem + 8192);

    const float* qc = ws + WS_QC;
    const int* flags = (const int*)(ws + WS_FLAG);
    const float* fi = ws + WS_FI;
    const float* fj = ws + WS_FJ;

    const int row = bi - 4;
    const int b = row / LSEQ;
    const int i = row - b * LSEQ;

    for (int j = t; j < LSEQ; j += 256) {
        int g = b * LSEQ + j;
        sx[j] = S[g * 3 + 0];
        sy[j] = S[g * 3 + 1];
        sz[j] = S[g * 3 + 2];
        sq[j] = qc[g];
        sf[j] = (unsigned char)flags[g];
    }
    if (t == 0) *cntL = 0;
    __syncthreads();

    const float six = sx[i], siy = sy[i], siz = sz[i], qi = sq[i];
    const int fli = sf[i];
    const bool posi = (fli & 1) != 0, negi = (fli & 2) != 0;
    const int lane = t & 63, w = t >> 6;
    float esum = 0.0f;
    float* mrow = out + OUT_MASK + (long)row * LSEQ;

    for (int j = t; j < LSEQ; j += 256) {
        float dx = __fsub_rn(six, sx[j]);
        float dy = __fsub_rn(siy, sy[j]);
        float dz = __fsub_rn(siz, sz[j]);
        float d2 = __fadd_rn(__fadd_rn(__fmul_rn(dx, dx), __fmul_rn(dy, dy)), __fmul_rn(dz, dz));
        d2 = __fadd_rn(d2, 1e-12f);
        float D = __fsqrt_rn(d2);
        mrow[j] = 0.0f;
        if (j > i && D < 15.0f && D > 0.0f) {
            float num = __fmul_rn(__fmul_rn(332.0f, qi), sq[j]);
            float den = __fmul_rn(__fmul_rn(20.0f, D), D);
            esum += __fdiv_rn(num, den);
        }
        int flj = sf[j];
        bool near = (D < 4.0f);
        bool need1 = near && posi && ((flj & 2) != 0);
        bool need2 = near && negi && ((flj & 1) != 0);
        if (need1 || need2) {
            int p = atomicAdd(cntL, 1);
            clist[p] = (unsigned int)j | (need1 ? 512u : 0u) | (need2 ? 1024u : 0u);
        }
    }
#pragma unroll
    for (int o = 32; o > 0; o >>= 1) esum += __shfl_xor(esum, o, 64);
    if (lane == 0) red[w] = esum;
    __syncthreads();
    if (t == 0) {
        float s = red[0] + red[1] + red[2] + red[3];
        atomicAdd(&out[OUT_EN + b], s);
    }

    int nc = *cntL;   // valid: barrier above
    if (nc == 0) return;

    for (int idx = t; idx < 2048; idx += 256)
        ((float4*)w2s)[idx] = ((const float4*)sW2)[idx];
    const float* dvec = sW1 + 1280 * 128;
    const float dv0 = dvec[lane], dv1 = dvec[lane + 64];
    const float sb0 = sb1[lane], sb1v = sb1[lane + 64];
    const float w3l = sW3[lane];
    const float b2v = sb2[lane];
    const float b3v = sb3[0];
    __syncthreads();

    for (int c = w; c < nc; c += 4) {
        unsigned int e = clist[c];
        int j = (int)(e & 511u);
        bool need1 = (e & 512u) != 0, need2 = (e & 1024u) != 0;
        float dx = __fsub_rn(six, sx[j]);
        float dy = __fsub_rn(siy, sy[j]);
        float dz = __fsub_rn(siz, sz[j]);
        float d2 = __fadd_rn(__fadd_rn(__fmul_rn(dx, dx), __fmul_rn(dy, dy)), __fmul_rn(dz, dz));
        d2 = __fadd_rn(d2, 1e-12f);
        float D = __fsqrt_rn(d2);
        int gi = row, gj = b * LSEQ + j;
        bool hit = false;
        if (need1) {
            float x = mlp_eval(fi, fj, gi, gj, D, dv0, dv1, sb0, sb1v, b2v, w3l, w2s, lane);
            hit = (x + b3v) > 0.0f;
        }
        if (!hit && need2) {
            float x = mlp_eval(fi, fj, gj, gi, D, dv0, dv1, sb0, sb1v, b2v, w3l, w2s, lane);
            hit = (x + b3v) > 0.0f;
        }
        if (hit && lane == 0) mrow[j] = 1.0f;
    }
}

extern "C" void kernel_launch(void* const* d_in, const int* in_sizes, int n_in,
                              void* d_out, int out_size, void* d_ws, size_t ws_size,
                              hipStream_t stream) {
    const float* X     = (const float*)d_in[0];
    const int*   seq   = (const int*)d_in[1];
    const float* S     = (const float*)d_in[2];
    const float* W1    = (const float*)d_in[3];
    const float* b1    = (const float*)d_in[4];
    const float* gam   = (const float*)d_in[5];
    const float* bet   = (const float*)d_in[6];
    const float* rmean = (const float*)d_in[7];
    const float* rvar  = (const float*)d_in[8];
    const float* W2    = (const float*)d_in[9];
    const float* b2    = (const float*)d_in[10];
    const float* W3    = (const float*)d_in[11];
    const float* b3    = (const float*)d_in[12];
    const float* sW1   = (const float*)d_in[13];
    const float* sb1   = (const float*)d_in[14];
    const float* sW2   = (const float*)d_in[15];
    const float* sb2   = (const float*)d_in[16];
    const float* sW3   = (const float*)d_in[17];
    const float* sb3   = (const float*)d_in[18];
    const float* c1w   = (const float*)d_in[19];
    const float* c1b   = (const float*)d_in[20];
    const float* c2w   = (const float*)d_in[21];
    const float* c2b   = (const float*)d_in[22];
    const float* c3w   = (const float*)d_in[23];
    const float* c3b   = (const float*)d_in[24];

    float* out = (float*)d_out;
    float* ws  = (float*)d_ws;

    hipLaunchKernelGGL(k_gemm, dim3(48, 6, 4), dim3(256), 0, stream, X, W1, sW1, ws, out);
    hipLaunchKernelGGL(k_row, dim3(384), dim3(256), 0, stream,
                       ws, b1, gam, bet, rmean, rvar, W2, b2, W3, b3, seq, out);
    hipLaunchKernelGGL(k2, dim3(1540), dim3(256), 0, stream,
                       S, ws, sW1, sb1, sW2, sb2, sW3, sb3,
                       c1w, c1b, c2w, c2b, c3w, c3b, out);
}